// Round 1
// baseline (301.441 us; speedup 1.0000x reference)
//
#include <hip/hip_runtime.h>

#define NA_   4096
#define NB_   4000
#define NANG_ 8000
#define NAC_  4000
#define ND_   12000
#define NDC_  6000
#define NI_   2000
#define EPS_  1e-12f

#define NBONDED (NB_ + NANG_ + NAC_ + ND_ + NDC_ + NI_)   // 36000
#define NPB   1024                                         // pair blocks (4 rows each)
#define NBB   ((NBONDED + 255) / 256)                      // 141 bonded blocks
#define NBLK  (NPB + NBB)
#define TILE  1024
#define NTILE (NA_ / TILE)
#define NCAND (NB_ + NANG_)                                // 12000 masked-pair candidates

struct F3 { float x, y, z; };

__device__ inline F3 ldp(const float* __restrict__ p, int i) {
    F3 r; r.x = p[3*i]; r.y = p[3*i+1]; r.z = p[3*i+2]; return r;
}
__device__ inline F3 sub3(F3 a, F3 b) { return {a.x-b.x, a.y-b.y, a.z-b.z}; }
__device__ inline float dot3(F3 a, F3 b) { return a.x*b.x + a.y*b.y + a.z*b.z; }
__device__ inline F3 cross3(F3 a, F3 b) {
    return {a.y*b.z - a.z*b.y, a.z*b.x - a.x*b.z, a.x*b.y - a.y*b.x};
}

__device__ inline float angle_(F3 p0, F3 p1, F3 p2) {
    F3 u = sub3(p0, p1), v = sub3(p2, p1);
    float c = dot3(u, v) * rsqrtf(dot3(u, u) * dot3(v, v) + EPS_);
    c = fminf(fmaxf(c, -1.0f + 1e-7f), 1.0f - 1e-7f);
    return acosf(c);
}

__device__ inline float dihedral_(F3 p0, F3 p1, F3 p2, F3 p3) {
    F3 b1 = sub3(p1, p0), b2 = sub3(p2, p1), b3 = sub3(p3, p2);
    F3 n1 = cross3(b1, b2), n2 = cross3(b2, b3);
    float ib = rsqrtf(dot3(b2, b2) + EPS_);
    F3 b2n = {b2.x * ib, b2.y * ib, b2.z * ib};
    return atan2f(dot3(cross3(n1, b2n), n2), dot3(n1, n2));
}

// Blocks [0,NPB): nonbonded, UNMASKED upper-triangle sum (mask never read here;
// the <=24000 masked-out pairs are subtracted in fin_k). Block b owns rows
// {2b, 2b+1, 4094-2b, 4095-2b} -> exactly 8190 pairs/block (perfect balance).
// j-atom data staged in LDS per 1024-tile; each thread reads its float4
// j-group from LDS ONCE and reuses it across all 4 rows (register caching).
// Blocks [NPB,NBLK): bonded.
__global__ __launch_bounds__(256) void main_k(
    const float* __restrict__ pos, const float* __restrict__ q,
    const float* __restrict__ eps, const float* __restrict__ sig,
    const float* __restrict__ bond_c,  const float* __restrict__ ang_c,
    const float* __restrict__ angc_c,  const float* __restrict__ dih_c,
    const float* __restrict__ dihc_c,  const float* __restrict__ imp_c,
    const int* __restrict__ bond_i,  const int* __restrict__ ang_i,
    const int* __restrict__ angc_i,  const int* __restrict__ dih_i,
    const int* __restrict__ dihc_i,  const int* __restrict__ imp_i,
    double* __restrict__ partials)
{
    __shared__ float sx[TILE], sy[TILE], sz[TILE], sq[TILE], se[TILE], ss[TILE];
    __shared__ double sred[256];
    const int tid = threadIdx.x;
    const int bid = blockIdx.x;
    double local = 0.0;

    if (bid < NPB) {
        const float SQC = 18.2299835f;  // sqrtf(332.33)
        int   irow[4];
        float rx[4], ry[4], rz[4], rq[4], re_[4], rs[4];
        irow[0] = 2 * bid;       irow[1] = 2 * bid + 1;
        irow[2] = 4094 - 2 * bid; irow[3] = 4095 - 2 * bid;
        #pragma unroll
        for (int r = 0; r < 4; ++r) {
            const int i = irow[r];
            rx[r] = pos[3*i]; ry[r] = pos[3*i+1]; rz[r] = pos[3*i+2];
            rq[r] = q[i] * SQC; re_[r] = sqrtf(eps[i]); rs[r] = sig[i];
        }

        const int t0 = (2 * bid + 1) >> 10;   // first tile the lowest row needs
        for (int t = t0; t < NTILE; ++t) {
            const int tbase = t << 10;
            __syncthreads();                   // protect previous-tile reads
            {
                // Fully vectorized stage: 4 atoms/thread, 6 float4 loads.
                const int a0 = 4 * tid;
                const int g0 = tbase + a0;
                const float4 pa = *(const float4*)(pos + 3*g0);
                const float4 pb = *(const float4*)(pos + 3*g0 + 4);
                const float4 pc = *(const float4*)(pos + 3*g0 + 8);
                const float4 q4 = *(const float4*)(q   + g0);
                const float4 e4 = *(const float4*)(eps + g0);
                const float4 s4 = *(const float4*)(sig + g0);
                *(float4*)&sx[a0] = make_float4(pa.x, pa.w, pb.z, pc.y);
                *(float4*)&sy[a0] = make_float4(pa.y, pb.x, pb.w, pc.z);
                *(float4*)&sz[a0] = make_float4(pa.z, pb.y, pc.x, pc.w);
                *(float4*)&sq[a0] = make_float4(q4.x*SQC, q4.y*SQC, q4.z*SQC, q4.w*SQC);
                *(float4*)&se[a0] = make_float4(sqrtf(e4.x), sqrtf(e4.y),
                                                sqrtf(e4.z), sqrtf(e4.w));
                *(float4*)&ss[a0] = s4;
            }
            __syncthreads();

            // Load this thread's j-group once; reuse across 4 rows.
            const int l  = 4 * tid;
            const int j4 = tbase + l;
            float xv[4], yv[4], zv[4], qv[4], ev[4], sv[4];
            *(float4*)xv = *(const float4*)&sx[l];
            *(float4*)yv = *(const float4*)&sy[l];
            *(float4*)zv = *(const float4*)&sz[l];
            *(float4*)qv = *(const float4*)&sq[l];
            *(float4*)ev = *(const float4*)&se[l];
            *(float4*)sv = *(const float4*)&ss[l];

            #pragma unroll
            for (int r = 0; r < 4; ++r) {
                const int i = irow[r];
                if (i + 1 >= tbase + TILE) continue;  // block-uniform skip
                if (j4 + 3 > i) {                     // wave-coherent skip
                    const float xi = rx[r], yi = ry[r], zi = rz[r];
                    const float qi = rq[r], ei = re_[r], si = rs[r];
                    float fsum = 0.0f;
                    #pragma unroll
                    for (int k = 0; k < 4; ++k) {
                        const int j = j4 + k;
                        const float dx = xi - xv[k];
                        const float dy = yi - yv[k];
                        const float dz = zi - zv[k];
                        const float r2 = dx*dx + dy*dy + dz*dz + EPS_;
                        const float inv_r = rsqrtf(r2);
                        const float eij = ei * ev[k];
                        const float sij = 0.5f * (si + sv[k]);
                        const float sr  = sij * inv_r;
                        const float s2  = sr * sr;
                        const float sr6 = s2 * s2 * s2;
                        const float en  = 4.0f * eij * (sr6*sr6 - sr6)
                                        + qi * qv[k] * inv_r;
                        fsum += (j > i) ? en : 0.0f;
                    }
                    local += (double)fsum;
                }
            }
        }
    } else {
        const int t = (bid - NPB) * 256 + tid;
        float e = 0.0f;
        if (t < NB_) {
            const int k = t;
            const int i0 = bond_i[3*k], i1 = bond_i[3*k+1], ty = bond_i[3*k+2];
            F3 d = sub3(ldp(pos, i0), ldp(pos, i1));
            const float r = sqrtf(dot3(d, d) + EPS_);
            const float dr = r - bond_c[2*ty+1];
            e = bond_c[2*ty] * dr * dr;
        } else if (t < NB_ + NANG_) {
            const int k = t - NB_;
            const int i0 = ang_i[4*k], i1 = ang_i[4*k+1], i2 = ang_i[4*k+2], ty = ang_i[4*k+3];
            const float th = angle_(ldp(pos, i0), ldp(pos, i1), ldp(pos, i2));
            const float dt = th - ang_c[2*ty+1];
            e = ang_c[2*ty] * dt * dt;
        } else if (t < NB_ + NANG_ + NAC_) {
            const int k = t - NB_ - NANG_;
            const int i0 = angc_i[4*k], i1 = angc_i[4*k+1], i2 = angc_i[4*k+2], ty = angc_i[4*k+3];
            const F3 p0 = ldp(pos, i0), p1 = ldp(pos, i1), p2 = ldp(pos, i2);
            const float th = angle_(p0, p1, p2);
            const F3 d13 = sub3(p0, p2);
            const float r13 = sqrtf(dot3(d13, d13) + EPS_);
            const float dt = th - angc_c[4*ty+1];
            const float du = r13 - angc_c[4*ty+3];
            e = angc_c[4*ty] * dt * dt + angc_c[4*ty+2] * du * du;
        } else if (t < NB_ + NANG_ + NAC_ + ND_) {
            const int k = t - NB_ - NANG_ - NAC_;
            const int i0 = dih_i[5*k], i1 = dih_i[5*k+1], i2 = dih_i[5*k+2],
                      i3 = dih_i[5*k+3], ty = dih_i[5*k+4];
            const float phi = dihedral_(ldp(pos,i0), ldp(pos,i1), ldp(pos,i2), ldp(pos,i3));
            const float c = cosf(phi);
            const float* A = dih_c + 5*ty;
            e = A[0] + c*(A[1] + c*(A[2] + c*(A[3] + c*A[4])));
        } else if (t < NB_ + NANG_ + NAC_ + ND_ + NDC_) {
            const int k = t - NB_ - NANG_ - NAC_ - ND_;
            const int i0 = dihc_i[5*k], i1 = dihc_i[5*k+1], i2 = dihc_i[5*k+2],
                      i3 = dihc_i[5*k+3], ty = dihc_i[5*k+4];
            const float phi = dihedral_(ldp(pos,i0), ldp(pos,i1), ldp(pos,i2), ldp(pos,i3));
            e = dihc_c[4*ty] * (1.0f + cosf(dihc_c[4*ty+1] * phi - dihc_c[4*ty+2]));
        } else if (t < NBONDED) {
            const int k = t - NB_ - NANG_ - NAC_ - ND_ - NDC_;
            const int i0 = imp_i[5*k], i1 = imp_i[5*k+1], i2 = imp_i[5*k+2],
                      i3 = imp_i[5*k+3], ty = imp_i[5*k+4];
            const float chi = dihedral_(ldp(pos,i0), ldp(pos,i1), ldp(pos,i2), ldp(pos,i3));
            const float dc = chi - imp_c[2*ty+1];
            e = imp_c[2*ty] * dc * dc;
        }
        local = (double)e;
    }

    sred[tid] = local;
    __syncthreads();
    for (int s = 128; s > 0; s >>= 1) {
        if (tid < s) sred[tid] += sred[tid + s];
        __syncthreads();
    }
    if (tid == 0) partials[bid] = sred[0];
}

// Finish kernel (1 block x 1024 threads):
//  Phase A: each candidate pair (bond i0-i1, angle a0-a2) writes its candidate
//           id into wsmap[lo<<12|hi] (plain stores; any race winner is fine —
//           all duplicates of a pair compute the identical energy).
//  Phase B: the unique winner per pair reads mask[lo][hi]; if 0, subtracts the
//           pair energy (same f32 op sequence as main_k) in double.
//  Then sums the NBLK block partials and writes the final float.
__global__ __launch_bounds__(1024) void fin_k(
    const float* __restrict__ pos, const float* __restrict__ q,
    const float* __restrict__ eps, const float* __restrict__ sig,
    const float* __restrict__ mask,
    const int* __restrict__ bond_i, const int* __restrict__ ang_i,
    const double* __restrict__ partials, unsigned int* __restrict__ wsmap,
    float* __restrict__ out)
{
    __shared__ double sred[1024];
    const int tid = threadIdx.x;
    const float SQC = 18.2299835f;

    // Phase A: mark candidates.
    for (int c = tid; c < NCAND; c += 1024) {
        int u, v;
        if (c < NB_) { u = bond_i[3*c]; v = bond_i[3*c+1]; }
        else { const int k = c - NB_; u = ang_i[4*k]; v = ang_i[4*k+2]; }
        if (u != v) {
            const int lo = min(u, v), hi = max(u, v);
            wsmap[(lo << 12) | hi] = (unsigned int)c;
        }
    }
    __threadfence();
    __syncthreads();

    // Phase B: unique winner per pair subtracts the masked-out energy.
    double local = 0.0;
    for (int c = tid; c < NCAND; c += 1024) {
        int u, v;
        if (c < NB_) { u = bond_i[3*c]; v = bond_i[3*c+1]; }
        else { const int k = c - NB_; u = ang_i[4*k]; v = ang_i[4*k+2]; }
        if (u != v) {
            const int lo = min(u, v), hi = max(u, v);
            if (wsmap[(lo << 12) | hi] == (unsigned int)c) {
                const float m = mask[(size_t)lo * NA_ + hi];
                if (m == 0.0f) {
                    // Replicate main_k's f32 sequence exactly (i=lo row, j=hi col).
                    const float dx = pos[3*lo]   - pos[3*hi];
                    const float dy = pos[3*lo+1] - pos[3*hi+1];
                    const float dz = pos[3*lo+2] - pos[3*hi+2];
                    const float r2 = dx*dx + dy*dy + dz*dz + EPS_;
                    const float inv_r = rsqrtf(r2);
                    const float eij = sqrtf(eps[lo]) * sqrtf(eps[hi]);
                    const float sij = 0.5f * (sig[lo] + sig[hi]);
                    const float sr  = sij * inv_r;
                    const float s2  = sr * sr;
                    const float sr6 = s2 * s2 * s2;
                    const float en  = 4.0f * eij * (sr6*sr6 - sr6)
                                    + (q[lo]*SQC) * (q[hi]*SQC) * inv_r;
                    local -= (double)en;
                }
            }
        }
    }

    // Final reduction: corrections + block partials.
    double s = local;
    for (int i = tid; i < NBLK; i += 1024) s += partials[i];
    sred[tid] = s;
    __syncthreads();
    for (int st = 512; st > 0; st >>= 1) {
        if (tid < st) sred[tid] += sred[tid + st];
        __syncthreads();
    }
    if (tid == 0) out[0] = (float)sred[0];
}

extern "C" void kernel_launch(void* const* d_in, const int* in_sizes, int n_in,
                              void* d_out, int out_size, void* d_ws, size_t ws_size,
                              hipStream_t stream) {
    const float* pos  = (const float*)d_in[0];
    const float* q    = (const float*)d_in[1];
    const float* eps  = (const float*)d_in[2];
    const float* sig  = (const float*)d_in[3];
    const float* mask = (const float*)d_in[4];
    const float* bond_c = (const float*)d_in[5];
    const float* ang_c  = (const float*)d_in[6];
    const float* angc_c = (const float*)d_in[7];
    const float* dih_c  = (const float*)d_in[8];
    const float* dihc_c = (const float*)d_in[9];
    const float* imp_c  = (const float*)d_in[10];
    const int* bond_i = (const int*)d_in[11];
    const int* ang_i  = (const int*)d_in[12];
    const int* angc_i = (const int*)d_in[13];
    const int* dih_i  = (const int*)d_in[14];
    const int* dihc_i = (const int*)d_in[15];
    const int* imp_i  = (const int*)d_in[16];
    // d_in[17] = pair_idx: deterministic triu_indices -- intentionally unread.

    // ws layout: [0, NBLK*8) partials; [16K, 16K+67.1MB) pair-dedup map.
    double* partials = (double*)d_ws;
    unsigned int* wsmap = (unsigned int*)((char*)d_ws + 16384);
    float* out = (float*)d_out;

    hipLaunchKernelGGL(main_k, dim3(NBLK), dim3(256), 0, stream,
                       pos, q, eps, sig,
                       bond_c, ang_c, angc_c, dih_c, dihc_c, imp_c,
                       bond_i, ang_i, angc_i, dih_i, dihc_i, imp_i, partials);
    hipLaunchKernelGGL(fin_k, dim3(1), dim3(1024), 0, stream,
                       pos, q, eps, sig, mask, bond_i, ang_i, partials, wsmap, out);
}

// Round 2
// 170.254 us; speedup vs baseline: 1.7705x; 1.7705x over previous
//
#include <hip/hip_runtime.h>

#define NA_   4096
#define NB_   4000
#define NANG_ 8000
#define NAC_  4000
#define ND_   12000
#define NDC_  6000
#define NI_   2000
#define EPS_  1e-12f

#define NBONDED (NB_ + NANG_ + NAC_ + ND_ + NDC_ + NI_)   // 36000
#define NPB   1024                                         // pair blocks (4 rows each)
#define NBB   ((NBONDED + 255) / 256)                      // 141 bonded blocks
#define NBLK  (NPB + NBB)
#define TILE  1024
#define NTILE (NA_ / TILE)
#define NCAND (NB_ + NANG_)                                // 12000 masked-pair candidates

struct F3 { float x, y, z; };

__device__ inline F3 ldp(const float* __restrict__ p, int i) {
    F3 r; r.x = p[3*i]; r.y = p[3*i+1]; r.z = p[3*i+2]; return r;
}
__device__ inline F3 sub3(F3 a, F3 b) { return {a.x-b.x, a.y-b.y, a.z-b.z}; }
__device__ inline float dot3(F3 a, F3 b) { return a.x*b.x + a.y*b.y + a.z*b.z; }
__device__ inline F3 cross3(F3 a, F3 b) {
    return {a.y*b.z - a.z*b.y, a.z*b.x - a.x*b.z, a.x*b.y - a.y*b.x};
}

__device__ inline float angle_(F3 p0, F3 p1, F3 p2) {
    F3 u = sub3(p0, p1), v = sub3(p2, p1);
    float c = dot3(u, v) * rsqrtf(dot3(u, u) * dot3(v, v) + EPS_);
    c = fminf(fmaxf(c, -1.0f + 1e-7f), 1.0f - 1e-7f);
    return acosf(c);
}

__device__ inline float dihedral_(F3 p0, F3 p1, F3 p2, F3 p3) {
    F3 b1 = sub3(p1, p0), b2 = sub3(p2, p1), b3 = sub3(p3, p2);
    F3 n1 = cross3(b1, b2), n2 = cross3(b2, b3);
    float ib = rsqrtf(dot3(b2, b2) + EPS_);
    F3 b2n = {b2.x * ib, b2.y * ib, b2.z * ib};
    return atan2f(dot3(cross3(n1, b2n), n2), dot3(n1, n2));
}

// Phase A: winner-takes-all candidate marks. Runs BEFORE main_k; the kernel
// boundary provides ordering + cross-XCD visibility (same mechanism the
// partials buffer relies on). Any race winner among duplicates of the same
// (lo,hi) pair is fine -- all duplicates compute identical energy.
__global__ __launch_bounds__(1024) void mark_k(
    const int* __restrict__ bond_i, const int* __restrict__ ang_i,
    unsigned int* __restrict__ wsmap)
{
    const int c = blockIdx.x * 1024 + threadIdx.x;
    if (c >= NCAND) return;
    int u, v;
    if (c < NB_) { u = bond_i[3*c]; v = bond_i[3*c+1]; }
    else { const int k = c - NB_; u = ang_i[4*k]; v = ang_i[4*k+2]; }
    if (u != v) {
        const int lo = min(u, v), hi = max(u, v);
        wsmap[(lo << 12) | hi] = (unsigned int)c;
    }
}

// Subtract the energy of one masked-out pair, replicating main_k's exact f32
// op sequence (i = lo row, j = hi col).
__device__ inline double masked_corr(
    const float* __restrict__ pos, const float* __restrict__ q,
    const float* __restrict__ eps, const float* __restrict__ sig,
    const float* __restrict__ mask, const unsigned int* __restrict__ wsmap,
    int u, int v, int c)
{
    const float SQC = 18.2299835f;
    if (u == v) return 0.0;
    const int lo = min(u, v), hi = max(u, v);
    if (wsmap[(lo << 12) | hi] != (unsigned int)c) return 0.0;  // not the winner
    if (mask[(size_t)lo * NA_ + hi] != 0.0f) return 0.0;        // not masked out
    const float dx = pos[3*lo]   - pos[3*hi];
    const float dy = pos[3*lo+1] - pos[3*hi+1];
    const float dz = pos[3*lo+2] - pos[3*hi+2];
    const float r2 = dx*dx + dy*dy + dz*dz + EPS_;
    const float inv_r = rsqrtf(r2);
    const float eij = sqrtf(eps[lo]) * sqrtf(eps[hi]);
    const float sij = 0.5f * (sig[lo] + sig[hi]);
    const float sr  = sij * inv_r;
    const float s2  = sr * sr;
    const float sr6 = s2 * s2 * s2;
    const float en  = 4.0f * eij * (sr6*sr6 - sr6)
                    + (q[lo]*SQC) * (q[hi]*SQC) * inv_r;
    return -(double)en;
}

// Blocks [0,NPB): nonbonded, UNMASKED upper-triangle sum (mask never streamed;
// the <=24000 masked-out pairs are subtracted by the bonded-branch threads
// below, using the phase-A map). Block b owns rows {2b, 2b+1, 4094-2b,
// 4095-2b} -> exactly 8190 pairs/block (perfect balance). j-atom data staged
// in LDS per 1024-tile; each thread reads its float4 j-group from LDS ONCE
// and reuses it across all 4 rows. Blocks [NPB,NBLK): bonded terms + phase-B
// corrections (scattered-load latency hidden under the 1024 pair blocks).
__global__ __launch_bounds__(256) void main_k(
    const float* __restrict__ pos, const float* __restrict__ q,
    const float* __restrict__ eps, const float* __restrict__ sig,
    const float* __restrict__ mask,
    const float* __restrict__ bond_c,  const float* __restrict__ ang_c,
    const float* __restrict__ angc_c,  const float* __restrict__ dih_c,
    const float* __restrict__ dihc_c,  const float* __restrict__ imp_c,
    const int* __restrict__ bond_i,  const int* __restrict__ ang_i,
    const int* __restrict__ angc_i,  const int* __restrict__ dih_i,
    const int* __restrict__ dihc_i,  const int* __restrict__ imp_i,
    const unsigned int* __restrict__ wsmap,
    double* __restrict__ partials)
{
    __shared__ float sx[TILE], sy[TILE], sz[TILE], sq[TILE], se[TILE], ss[TILE];
    __shared__ double sred[256];
    const int tid = threadIdx.x;
    const int bid = blockIdx.x;
    double local = 0.0;

    if (bid < NPB) {
        const float SQC = 18.2299835f;  // sqrtf(332.33)
        int   irow[4];
        float rx[4], ry[4], rz[4], rq[4], re_[4], rs[4];
        irow[0] = 2 * bid;       irow[1] = 2 * bid + 1;
        irow[2] = 4094 - 2 * bid; irow[3] = 4095 - 2 * bid;
        #pragma unroll
        for (int r = 0; r < 4; ++r) {
            const int i = irow[r];
            rx[r] = pos[3*i]; ry[r] = pos[3*i+1]; rz[r] = pos[3*i+2];
            rq[r] = q[i] * SQC; re_[r] = sqrtf(eps[i]); rs[r] = sig[i];
        }

        const int t0 = (2 * bid + 1) >> 10;   // first tile the lowest row needs
        for (int t = t0; t < NTILE; ++t) {
            const int tbase = t << 10;
            __syncthreads();                   // protect previous-tile reads
            {
                // Fully vectorized stage: 4 atoms/thread, 6 float4 loads.
                const int a0 = 4 * tid;
                const int g0 = tbase + a0;
                const float4 pa = *(const float4*)(pos + 3*g0);
                const float4 pb = *(const float4*)(pos + 3*g0 + 4);
                const float4 pc = *(const float4*)(pos + 3*g0 + 8);
                const float4 q4 = *(const float4*)(q   + g0);
                const float4 e4 = *(const float4*)(eps + g0);
                const float4 s4 = *(const float4*)(sig + g0);
                *(float4*)&sx[a0] = make_float4(pa.x, pa.w, pb.z, pc.y);
                *(float4*)&sy[a0] = make_float4(pa.y, pb.x, pb.w, pc.z);
                *(float4*)&sz[a0] = make_float4(pa.z, pb.y, pc.x, pc.w);
                *(float4*)&sq[a0] = make_float4(q4.x*SQC, q4.y*SQC, q4.z*SQC, q4.w*SQC);
                *(float4*)&se[a0] = make_float4(sqrtf(e4.x), sqrtf(e4.y),
                                                sqrtf(e4.z), sqrtf(e4.w));
                *(float4*)&ss[a0] = s4;
            }
            __syncthreads();

            // Load this thread's j-group once; reuse across 4 rows.
            const int l  = 4 * tid;
            const int j4 = tbase + l;
            float xv[4], yv[4], zv[4], qv[4], ev[4], sv[4];
            *(float4*)xv = *(const float4*)&sx[l];
            *(float4*)yv = *(const float4*)&sy[l];
            *(float4*)zv = *(const float4*)&sz[l];
            *(float4*)qv = *(const float4*)&sq[l];
            *(float4*)ev = *(const float4*)&se[l];
            *(float4*)sv = *(const float4*)&ss[l];

            #pragma unroll
            for (int r = 0; r < 4; ++r) {
                const int i = irow[r];
                if (i + 1 >= tbase + TILE) continue;  // block-uniform skip
                if (j4 + 3 > i) {                     // wave-coherent skip
                    const float xi = rx[r], yi = ry[r], zi = rz[r];
                    const float qi = rq[r], ei = re_[r], si = rs[r];
                    float fsum = 0.0f;
                    #pragma unroll
                    for (int k = 0; k < 4; ++k) {
                        const int j = j4 + k;
                        const float dx = xi - xv[k];
                        const float dy = yi - yv[k];
                        const float dz = zi - zv[k];
                        const float r2 = dx*dx + dy*dy + dz*dz + EPS_;
                        const float inv_r = rsqrtf(r2);
                        const float eij = ei * ev[k];
                        const float sij = 0.5f * (si + sv[k]);
                        const float sr  = sij * inv_r;
                        const float s2  = sr * sr;
                        const float sr6 = s2 * s2 * s2;
                        const float en  = 4.0f * eij * (sr6*sr6 - sr6)
                                        + qi * qv[k] * inv_r;
                        fsum += (j > i) ? en : 0.0f;
                    }
                    local += (double)fsum;
                }
            }
        }
    } else {
        const int t = (bid - NPB) * 256 + tid;
        float e = 0.0f;
        if (t < NB_) {
            const int k = t;
            const int i0 = bond_i[3*k], i1 = bond_i[3*k+1], ty = bond_i[3*k+2];
            F3 d = sub3(ldp(pos, i0), ldp(pos, i1));
            const float r = sqrtf(dot3(d, d) + EPS_);
            const float dr = r - bond_c[2*ty+1];
            e = bond_c[2*ty] * dr * dr;
            // Phase-B correction: candidate id c == t, pair (i0, i1).
            local += masked_corr(pos, q, eps, sig, mask, wsmap, i0, i1, t);
        } else if (t < NB_ + NANG_) {
            const int k = t - NB_;
            const int i0 = ang_i[4*k], i1 = ang_i[4*k+1], i2 = ang_i[4*k+2], ty = ang_i[4*k+3];
            const float th = angle_(ldp(pos, i0), ldp(pos, i1), ldp(pos, i2));
            const float dt = th - ang_c[2*ty+1];
            e = ang_c[2*ty] * dt * dt;
            // Phase-B correction: candidate id c == t, pair (i0, i2).
            local += masked_corr(pos, q, eps, sig, mask, wsmap, i0, i2, t);
        } else if (t < NB_ + NANG_ + NAC_) {
            const int k = t - NB_ - NANG_;
            const int i0 = angc_i[4*k], i1 = angc_i[4*k+1], i2 = angc_i[4*k+2], ty = angc_i[4*k+3];
            const F3 p0 = ldp(pos, i0), p1 = ldp(pos, i1), p2 = ldp(pos, i2);
            const float th = angle_(p0, p1, p2);
            const F3 d13 = sub3(p0, p2);
            const float r13 = sqrtf(dot3(d13, d13) + EPS_);
            const float dt = th - angc_c[4*ty+1];
            const float du = r13 - angc_c[4*ty+3];
            e = angc_c[4*ty] * dt * dt + angc_c[4*ty+2] * du * du;
        } else if (t < NB_ + NANG_ + NAC_ + ND_) {
            const int k = t - NB_ - NANG_ - NAC_;
            const int i0 = dih_i[5*k], i1 = dih_i[5*k+1], i2 = dih_i[5*k+2],
                      i3 = dih_i[5*k+3], ty = dih_i[5*k+4];
            const float phi = dihedral_(ldp(pos,i0), ldp(pos,i1), ldp(pos,i2), ldp(pos,i3));
            const float c = cosf(phi);
            const float* A = dih_c + 5*ty;
            e = A[0] + c*(A[1] + c*(A[2] + c*(A[3] + c*A[4])));
        } else if (t < NB_ + NANG_ + NAC_ + ND_ + NDC_) {
            const int k = t - NB_ - NANG_ - NAC_ - ND_;
            const int i0 = dihc_i[5*k], i1 = dihc_i[5*k+1], i2 = dihc_i[5*k+2],
                      i3 = dihc_i[5*k+3], ty = dihc_i[5*k+4];
            const float phi = dihedral_(ldp(pos,i0), ldp(pos,i1), ldp(pos,i2), ldp(pos,i3));
            e = dihc_c[4*ty] * (1.0f + cosf(dihc_c[4*ty+1] * phi - dihc_c[4*ty+2]));
        } else if (t < NBONDED) {
            const int k = t - NB_ - NANG_ - NAC_ - ND_ - NDC_;
            const int i0 = imp_i[5*k], i1 = imp_i[5*k+1], i2 = imp_i[5*k+2],
                      i3 = imp_i[5*k+3], ty = imp_i[5*k+4];
            const float chi = dihedral_(ldp(pos,i0), ldp(pos,i1), ldp(pos,i2), ldp(pos,i3));
            const float dc = chi - imp_c[2*ty+1];
            e = imp_c[2*ty] * dc * dc;
        }
        local += (double)e;
    }

    sred[tid] = local;
    __syncthreads();
    for (int s = 128; s > 0; s >>= 1) {
        if (tid < s) sred[tid] += sred[tid + s];
        __syncthreads();
    }
    if (tid == 0) partials[bid] = sred[0];
}

__global__ __launch_bounds__(256) void fin_k(const double* __restrict__ partials,
                                             float* __restrict__ out) {
    __shared__ double sred[256];
    const int tid = threadIdx.x;
    double s = 0.0;
    for (int i = tid; i < NBLK; i += 256) s += partials[i];
    sred[tid] = s;
    __syncthreads();
    for (int st = 128; st > 0; st >>= 1) {
        if (tid < st) sred[tid] += sred[tid + st];
        __syncthreads();
    }
    if (tid == 0) out[0] = (float)sred[0];
}

extern "C" void kernel_launch(void* const* d_in, const int* in_sizes, int n_in,
                              void* d_out, int out_size, void* d_ws, size_t ws_size,
                              hipStream_t stream) {
    const float* pos  = (const float*)d_in[0];
    const float* q    = (const float*)d_in[1];
    const float* eps  = (const float*)d_in[2];
    const float* sig  = (const float*)d_in[3];
    const float* mask = (const float*)d_in[4];
    const float* bond_c = (const float*)d_in[5];
    const float* ang_c  = (const float*)d_in[6];
    const float* angc_c = (const float*)d_in[7];
    const float* dih_c  = (const float*)d_in[8];
    const float* dihc_c = (const float*)d_in[9];
    const float* imp_c  = (const float*)d_in[10];
    const int* bond_i = (const int*)d_in[11];
    const int* ang_i  = (const int*)d_in[12];
    const int* angc_i = (const int*)d_in[13];
    const int* dih_i  = (const int*)d_in[14];
    const int* dihc_i = (const int*)d_in[15];
    const int* imp_i  = (const int*)d_in[16];
    // d_in[17] = pair_idx: deterministic triu_indices -- intentionally unread.

    // ws layout: [0, NBLK*8) partials; [16K, 16K+67.1MB) pair-dedup map.
    double* partials = (double*)d_ws;
    unsigned int* wsmap = (unsigned int*)((char*)d_ws + 16384);
    float* out = (float*)d_out;

    hipLaunchKernelGGL(mark_k, dim3((NCAND + 1023) / 1024), dim3(1024), 0, stream,
                       bond_i, ang_i, wsmap);
    hipLaunchKernelGGL(main_k, dim3(NBLK), dim3(256), 0, stream,
                       pos, q, eps, sig, mask,
                       bond_c, ang_c, angc_c, dih_c, dihc_c, imp_c,
                       bond_i, ang_i, angc_i, dih_i, dihc_i, imp_i, wsmap, partials);
    hipLaunchKernelGGL(fin_k, dim3(1), dim3(256), 0, stream, partials, out);
}

// Round 3
// 167.403 us; speedup vs baseline: 1.8007x; 1.0170x over previous
//
#include <hip/hip_runtime.h>

#define NA_   4096
#define NB_   4000
#define NANG_ 8000
#define NAC_  4000
#define ND_   12000
#define NDC_  6000
#define NI_   2000
#define EPS_  1e-12f

#define NBONDED (NB_ + NANG_ + NAC_ + ND_ + NDC_ + NI_)   // 36000
#define NPB   1024                                         // pair blocks (4 rows each)
#define NBB   ((NBONDED + 255) / 256)                      // 141 bonded blocks
#define NBLK  (NPB + NBB)
#define TILE  1024
#define NTILE (NA_ / TILE)

struct F3 { float x, y, z; };

__device__ inline F3 ldp(const float* __restrict__ p, int i) {
    F3 r; r.x = p[3*i]; r.y = p[3*i+1]; r.z = p[3*i+2]; return r;
}
__device__ inline F3 sub3(F3 a, F3 b) { return {a.x-b.x, a.y-b.y, a.z-b.z}; }
__device__ inline float dot3(F3 a, F3 b) { return a.x*b.x + a.y*b.y + a.z*b.z; }
__device__ inline F3 cross3(F3 a, F3 b) {
    return {a.y*b.z - a.z*b.y, a.z*b.x - a.x*b.z, a.x*b.y - a.y*b.x};
}

__device__ inline float angle_(F3 p0, F3 p1, F3 p2) {
    F3 u = sub3(p0, p1), v = sub3(p2, p1);
    float c = dot3(u, v) * rsqrtf(dot3(u, u) * dot3(v, v) + EPS_);
    c = fminf(fmaxf(c, -1.0f + 1e-7f), 1.0f - 1e-7f);
    return acosf(c);
}

__device__ inline float dihedral_(F3 p0, F3 p1, F3 p2, F3 p3) {
    F3 b1 = sub3(p1, p0), b2 = sub3(p2, p1), b3 = sub3(p3, p2);
    F3 n1 = cross3(b1, b2), n2 = cross3(b2, b3);
    float ib = rsqrtf(dot3(b2, b2) + EPS_);
    F3 b2n = {b2.x * ib, b2.y * ib, b2.z * ib};
    return atan2f(dot3(cross3(n1, b2n), n2), dot3(n1, n2));
}

// Blocks [0,NPB): nonbonded. Block b owns rows {2b, 2b+1, 4094-2b, 4095-2b}
// -> exactly 8190 pairs/block (perfect balance). j-atom data staged in LDS
// per 1024-tile; each thread reads its float4 j-group from LDS ONCE and
// reuses it across all 4 rows (register caching).
// Op-count folds (bit-exact vs the reference sequence):
//   se/re_ hold 2*sqrt(eps)  -> eij = ei*ev == 4*sqrt(ei)*sqrt(ej) exactly
//   ss/rs  hold 0.5*sig      -> sij = si+sv == 0.5*(sig_i+sig_j) exactly
// Blocks [NPB,NBLK): bonded.
__global__ __launch_bounds__(256) void main_k(
    const float* __restrict__ pos, const float* __restrict__ q,
    const float* __restrict__ eps, const float* __restrict__ sig,
    const float* __restrict__ mask,
    const float* __restrict__ bond_c,  const float* __restrict__ ang_c,
    const float* __restrict__ angc_c,  const float* __restrict__ dih_c,
    const float* __restrict__ dihc_c,  const float* __restrict__ imp_c,
    const int* __restrict__ bond_i,  const int* __restrict__ ang_i,
    const int* __restrict__ angc_i,  const int* __restrict__ dih_i,
    const int* __restrict__ dihc_i,  const int* __restrict__ imp_i,
    double* __restrict__ partials)
{
    __shared__ float sx[TILE], sy[TILE], sz[TILE], sq[TILE], se[TILE], ss[TILE];
    __shared__ double sred[256];
    const int tid = threadIdx.x;
    const int bid = blockIdx.x;
    double local = 0.0;

    if (bid < NPB) {
        const float SQC = 18.2299835f;  // sqrtf(332.33)
        int   irow[4];
        float rx[4], ry[4], rz[4], rq[4], re_[4], rs[4];
        irow[0] = 2 * bid;       irow[1] = 2 * bid + 1;
        irow[2] = 4094 - 2 * bid; irow[3] = 4095 - 2 * bid;
        #pragma unroll
        for (int r = 0; r < 4; ++r) {
            const int i = irow[r];
            rx[r] = pos[3*i]; ry[r] = pos[3*i+1]; rz[r] = pos[3*i+2];
            rq[r] = q[i] * SQC;
            re_[r] = 2.0f * sqrtf(eps[i]);
            rs[r] = 0.5f * sig[i];
        }

        const int t0 = (2 * bid + 1) >> 10;   // first tile the lowest row needs
        for (int t = t0; t < NTILE; ++t) {
            const int tbase = t << 10;
            __syncthreads();                   // protect previous-tile reads
            {
                // Fully vectorized stage: 4 atoms/thread, 6 float4 loads.
                const int a0 = 4 * tid;
                const int g0 = tbase + a0;
                const float4 pa = *(const float4*)(pos + 3*g0);
                const float4 pb = *(const float4*)(pos + 3*g0 + 4);
                const float4 pc = *(const float4*)(pos + 3*g0 + 8);
                const float4 q4 = *(const float4*)(q   + g0);
                const float4 e4 = *(const float4*)(eps + g0);
                const float4 s4 = *(const float4*)(sig + g0);
                *(float4*)&sx[a0] = make_float4(pa.x, pa.w, pb.z, pc.y);
                *(float4*)&sy[a0] = make_float4(pa.y, pb.x, pb.w, pc.z);
                *(float4*)&sz[a0] = make_float4(pa.z, pb.y, pc.x, pc.w);
                *(float4*)&sq[a0] = make_float4(q4.x*SQC, q4.y*SQC, q4.z*SQC, q4.w*SQC);
                *(float4*)&se[a0] = make_float4(2.0f*sqrtf(e4.x), 2.0f*sqrtf(e4.y),
                                                2.0f*sqrtf(e4.z), 2.0f*sqrtf(e4.w));
                *(float4*)&ss[a0] = make_float4(0.5f*s4.x, 0.5f*s4.y,
                                                0.5f*s4.z, 0.5f*s4.w);
            }
            __syncthreads();

            // Load this thread's j-group once; reuse across 4 rows.
            const int l  = 4 * tid;
            const int j4 = tbase + l;
            float xv[4], yv[4], zv[4], qv[4], ev[4], sv[4];
            *(float4*)xv = *(const float4*)&sx[l];
            *(float4*)yv = *(const float4*)&sy[l];
            *(float4*)zv = *(const float4*)&sz[l];
            *(float4*)qv = *(const float4*)&sq[l];
            *(float4*)ev = *(const float4*)&se[l];
            *(float4*)sv = *(const float4*)&ss[l];

            #pragma unroll
            for (int r = 0; r < 4; ++r) {
                const int i = irow[r];
                if (i + 1 >= tbase + TILE) continue;  // block-uniform skip
                if (j4 + 3 > i) {                     // wave-coherent skip
                    const float4 m4 = *(const float4*)(mask + (size_t)i * NA_ + j4);
                    float mv[4]; *(float4*)mv = m4;
                    const float xi = rx[r], yi = ry[r], zi = rz[r];
                    const float qi = rq[r], ei = re_[r], si = rs[r];
                    float fsum = 0.0f;
                    #pragma unroll
                    for (int k = 0; k < 4; ++k) {
                        const int j = j4 + k;
                        const float dx = xi - xv[k];
                        const float dy = yi - yv[k];
                        const float dz = zi - zv[k];
                        const float r2 = dx*dx + dy*dy + dz*dz + EPS_;
                        const float inv_r = rsqrtf(r2);
                        const float eij4 = ei * ev[k];       // == 4*eps_ij
                        const float sij  = si + sv[k];       // == 0.5*(sig_i+sig_j)
                        const float sr  = sij * inv_r;
                        const float s2  = sr * sr;
                        const float sr6 = s2 * s2 * s2;
                        const float en  = eij4 * (sr6*sr6 - sr6)
                                        + qi * qv[k] * inv_r;
                        fsum += (j > i) ? mv[k] * en : 0.0f;
                    }
                    local += (double)fsum;
                }
            }
        }
    } else {
        const int t = (bid - NPB) * 256 + tid;
        float e = 0.0f;
        if (t < NB_) {
            const int k = t;
            const int i0 = bond_i[3*k], i1 = bond_i[3*k+1], ty = bond_i[3*k+2];
            F3 d = sub3(ldp(pos, i0), ldp(pos, i1));
            const float r = sqrtf(dot3(d, d) + EPS_);
            const float dr = r - bond_c[2*ty+1];
            e = bond_c[2*ty] * dr * dr;
        } else if (t < NB_ + NANG_) {
            const int k = t - NB_;
            const int i0 = ang_i[4*k], i1 = ang_i[4*k+1], i2 = ang_i[4*k+2], ty = ang_i[4*k+3];
            const float th = angle_(ldp(pos, i0), ldp(pos, i1), ldp(pos, i2));
            const float dt = th - ang_c[2*ty+1];
            e = ang_c[2*ty] * dt * dt;
        } else if (t < NB_ + NANG_ + NAC_) {
            const int k = t - NB_ - NANG_;
            const int i0 = angc_i[4*k], i1 = angc_i[4*k+1], i2 = angc_i[4*k+2], ty = angc_i[4*k+3];
            const F3 p0 = ldp(pos, i0), p1 = ldp(pos, i1), p2 = ldp(pos, i2);
            const float th = angle_(p0, p1, p2);
            const F3 d13 = sub3(p0, p2);
            const float r13 = sqrtf(dot3(d13, d13) + EPS_);
            const float dt = th - angc_c[4*ty+1];
            const float du = r13 - angc_c[4*ty+3];
            e = angc_c[4*ty] * dt * dt + angc_c[4*ty+2] * du * du;
        } else if (t < NB_ + NANG_ + NAC_ + ND_) {
            const int k = t - NB_ - NANG_ - NAC_;
            const int i0 = dih_i[5*k], i1 = dih_i[5*k+1], i2 = dih_i[5*k+2],
                      i3 = dih_i[5*k+3], ty = dih_i[5*k+4];
            const float phi = dihedral_(ldp(pos,i0), ldp(pos,i1), ldp(pos,i2), ldp(pos,i3));
            const float c = cosf(phi);
            const float* A = dih_c + 5*ty;
            e = A[0] + c*(A[1] + c*(A[2] + c*(A[3] + c*A[4])));
        } else if (t < NB_ + NANG_ + NAC_ + ND_ + NDC_) {
            const int k = t - NB_ - NANG_ - NAC_ - ND_;
            const int i0 = dihc_i[5*k], i1 = dihc_i[5*k+1], i2 = dihc_i[5*k+2],
                      i3 = dihc_i[5*k+3], ty = dihc_i[5*k+4];
            const float phi = dihedral_(ldp(pos,i0), ldp(pos,i1), ldp(pos,i2), ldp(pos,i3));
            e = dihc_c[4*ty] * (1.0f + cosf(dihc_c[4*ty+1] * phi - dihc_c[4*ty+2]));
        } else if (t < NBONDED) {
            const int k = t - NB_ - NANG_ - NAC_ - ND_ - NDC_;
            const int i0 = imp_i[5*k], i1 = imp_i[5*k+1], i2 = imp_i[5*k+2],
                      i3 = imp_i[5*k+3], ty = imp_i[5*k+4];
            const float chi = dihedral_(ldp(pos,i0), ldp(pos,i1), ldp(pos,i2), ldp(pos,i3));
            const float dc = chi - imp_c[2*ty+1];
            e = imp_c[2*ty] * dc * dc;
        }
        local = (double)e;
    }

    sred[tid] = local;
    __syncthreads();
    for (int s = 128; s > 0; s >>= 1) {
        if (tid < s) sred[tid] += sred[tid + s];
        __syncthreads();
    }
    if (tid == 0) partials[bid] = sred[0];
}

__global__ __launch_bounds__(256) void fin_k(const double* __restrict__ partials,
                                             float* __restrict__ out) {
    __shared__ double sred[256];
    const int tid = threadIdx.x;
    double s = 0.0;
    for (int i = tid; i < NBLK; i += 256) s += partials[i];
    sred[tid] = s;
    __syncthreads();
    for (int st = 128; st > 0; st >>= 1) {
        if (tid < st) sred[tid] += sred[tid + st];
        __syncthreads();
    }
    if (tid == 0) out[0] = (float)sred[0];
}

extern "C" void kernel_launch(void* const* d_in, const int* in_sizes, int n_in,
                              void* d_out, int out_size, void* d_ws, size_t ws_size,
                              hipStream_t stream) {
    const float* pos  = (const float*)d_in[0];
    const float* q    = (const float*)d_in[1];
    const float* eps  = (const float*)d_in[2];
    const float* sig  = (const float*)d_in[3];
    const float* mask = (const float*)d_in[4];
    const float* bond_c = (const float*)d_in[5];
    const float* ang_c  = (const float*)d_in[6];
    const float* angc_c = (const float*)d_in[7];
    const float* dih_c  = (const float*)d_in[8];
    const float* dihc_c = (const float*)d_in[9];
    const float* imp_c  = (const float*)d_in[10];
    const int* bond_i = (const int*)d_in[11];
    const int* ang_i  = (const int*)d_in[12];
    const int* angc_i = (const int*)d_in[13];
    const int* dih_i  = (const int*)d_in[14];
    const int* dihc_i = (const int*)d_in[15];
    const int* imp_i  = (const int*)d_in[16];
    // d_in[17] = pair_idx: deterministic triu_indices -- intentionally unread.

    double* partials = (double*)d_ws;   // NBLK doubles; every slot written.
    float* out = (float*)d_out;

    hipLaunchKernelGGL(main_k, dim3(NBLK), dim3(256), 0, stream,
                       pos, q, eps, sig, mask,
                       bond_c, ang_c, angc_c, dih_c, dihc_c, imp_c,
                       bond_i, ang_i, angc_i, dih_i, dihc_i, imp_i, partials);
    hipLaunchKernelGGL(fin_k, dim3(1), dim3(256), 0, stream, partials, out);
}